// Round 3
// baseline (118.226 us; speedup 1.0000x reference)
//
#include <hip/hip_runtime.h>

// LocalAggregator: semantic splatting of P=2048 3D Gaussians onto a 60x60x36
// voxel grid (N=129600 points), C=13 channels.
//
// Round 3 strategy (latency-bound fix):
//   K1 precompute: per-Gaussian record (24 floats: mean, log2(opac),
//      -0.5*log2e*icov with 2x folded off-diags, 13 sem) + int4 box.
//   K2 build_lists: one survivor list per 4x4x4 voxel brick (2025 bricks).
//      2025 blocks x 256 thr -> all 4.1M box tests fully parallel, removed
//      from the agg critical path.
//   K3 agg: ONE WAVE per brick (64 thr = 64 voxels), no LDS, no barriers,
//      no inner-loop branches. Every list entry overlaps the brick, so every
//      iteration is a full eval. Per-Gaussian loads are wave-uniform ->
//      scalar s_load pipelining; iterations independent -> unrollable.

constexpr int   HH      = 60;
constexpr int   WW      = 60;
constexpr int   DD      = 36;
constexpr int   P_N     = 2048;
constexpr int   C_N     = 13;
constexpr int   REC     = 24;     // floats per Gaussian record (6 x float4)
constexpr int   BX      = 15;     // bricks in x (60/4)
constexpr int   BY      = 15;     // bricks in y
constexpr int   BZ      = 9;      // bricks in z (36/4)
constexpr int   NBRICK  = BX * BY * BZ;   // 2025
constexpr int   MAXL    = 256;    // list capacity/brick (worst-case E~126)
constexpr float GRID_SZ = 0.08f;

__global__ void precompute_kernel(const float* __restrict__ means,
                                  const float* __restrict__ opac,
                                  const float* __restrict__ sem,
                                  const float* __restrict__ scales,
                                  const float* __restrict__ cov,
                                  const float* __restrict__ origin,
                                  float* __restrict__ recs,
                                  int4* __restrict__ boxes) {
    int g = blockIdx.x * blockDim.x + threadIdx.x;
    if (g >= P_N) return;
    float mx = means[g * 3 + 0], my = means[g * 3 + 1], mz = means[g * 3 + 2];
    float sx = scales[g * 3 + 0], sy = scales[g * 3 + 1], sz = scales[g * 3 + 2];
    float smax = fmaxf(sx, fmaxf(sy, sz));
    int rad = (int)ceilf(smax * 3.0f / GRID_SZ);
    float ox = origin[0], oy = origin[1], oz = origin[2];
    // match reference: ((means - origin) / GRID).astype(int32)  (trunc toward 0)
    int mix = (int)((mx - ox) / GRID_SZ);
    int miy = (int)((my - oy) / GRID_SZ);
    int miz = (int)((mz - oz) / GRID_SZ);
    const float* cv = cov + g * 9;
    // packed = (xx, yy, zz, xy, yz, xz) = flat indices [0,4,8,1,5,2]
    float a = cv[0], b = cv[4], c = cv[8], d = cv[1], e = cv[5], f = cv[2];
    float det = a * (b * c - e * e) - d * (d * c - e * f) + f * (d * e - b * f);
    const float kD = -0.5f * 1.44269504088896340736f;  // -0.5 * log2(e)
    const float kO = -1.44269504088896340736f;         // folds the 2x off-diag
    float* r = recs + g * REC;
    r[0] = mx; r[1] = my; r[2] = mz;
    r[3] = __log2f(opac[g]);
    r[4] = kD * (b * c - e * e) / det;   // c_xx
    r[5] = kD * (a * c - f * f) / det;   // c_yy
    r[6] = kD * (a * b - d * d) / det;   // c_zz
    r[7] = kO * (e * f - d * c) / det;   // c_xy
    r[8] = kO * (d * f - a * e) / det;   // c_yz
    r[9] = kO * (d * e - b * f) / det;   // c_xz
#pragma unroll
    for (int cc = 0; cc < C_N; ++cc) r[10 + cc] = sem[g * C_N + cc];
    r[23] = 0.0f;
    boxes[g] = make_int4(mix, miy, miz, rad);
}

__global__ __launch_bounds__(256) void build_lists(const int4* __restrict__ boxes,
                                                   int* __restrict__ lists,
                                                   int* __restrict__ counts) {
    __shared__ int s_cnt;
    __shared__ int s_idx[MAXL];
    const int b = (int)blockIdx.x;
    const int bk = b % BZ; const int rem = b / BZ;
    const int bj = rem % BY; const int bi = rem / BY;
    const int i0 = bi * 4, j0 = bj * 4, k0 = bk * 4;
    if (threadIdx.x == 0) s_cnt = 0;
    __syncthreads();
    for (int g = (int)threadIdx.x; g < P_N; g += 256) {
        int4 bx = boxes[g];
        bool ov = (bx.x - bx.w <= i0 + 3) && (bx.x + bx.w >= i0)
               && (bx.y - bx.w <= j0 + 3) && (bx.y + bx.w >= j0)
               && (bx.z - bx.w <= k0 + 3) && (bx.z + bx.w >= k0);
        if (ov) {
            int t = atomicAdd(&s_cnt, 1);
            if (t < MAXL) s_idx[t] = g;
        }
    }
    __syncthreads();
    const int c = min(s_cnt, MAXL);
    if (threadIdx.x == 0) counts[b] = c;
    for (int t = (int)threadIdx.x; t < c; t += 256)
        lists[b * MAXL + t] = s_idx[t];
}

__global__ __launch_bounds__(64) void agg_kernel(const float* __restrict__ recs,
                                                 const int4* __restrict__ boxes,
                                                 const int* __restrict__ lists,
                                                 const int* __restrict__ counts,
                                                 const float* __restrict__ origin,
                                                 float* __restrict__ out) {
    const int b = (int)blockIdx.x;
    const int bk = b % BZ; const int rem = b / BZ;
    const int bj = rem % BY; const int bi = rem / BY;
    const int lane = (int)threadIdx.x;
    const int kk = lane & 3, lj = (lane >> 2) & 3, li = lane >> 4;
    const int gi = bi * 4 + li, gj = bj * 4 + lj, k = bk * 4 + kk;
    // bit-exact replication of reference pts = (i + 0.5f) * GRID in fp32
    const float px = ((float)gi + 0.5f) * GRID_SZ;
    const float py = ((float)gj + 0.5f) * GRID_SZ;
    const float pz = ((float)k  + 0.5f) * GRID_SZ;
    const float ox = origin[0], oy = origin[1], oz = origin[2];
    const int pix = (int)((px - ox) / GRID_SZ);
    const int piy = (int)((py - oy) / GRID_SZ);
    const int piz = (int)((pz - oz) / GRID_SZ);

    const int cnt = counts[b];
    const int* __restrict__ lst = lists + b * MAXL;

    float acc[C_N];
#pragma unroll
    for (int cc = 0; cc < C_N; ++cc) acc[cc] = 0.0f;

#pragma unroll 2
    for (int i = 0; i < cnt; ++i) {
        const int g = lst[i];                     // wave-uniform -> s_load
        const float4* rp = (const float4*)(recs + (long)g * REC);
        const float4 r0 = rp[0];   // mean.xyz, log2(opac)
        const float4 r1 = rp[1];   // c_xx c_yy c_zz c_xy
        const float4 r2 = rp[2];   // c_yz c_xz sem0 sem1
        const float4 r3 = rp[3];   // sem2..5
        const float4 r4 = rp[4];   // sem6..9
        const float4 r5 = rp[5];   // sem10..12, pad
        const int4   bx = boxes[g];
        const bool inbox = (abs(pix - bx.x) <= bx.w)
                        && (abs(piy - bx.y) <= bx.w)
                        && (abs(piz - bx.z) <= bx.w);
        const float dx = px - r0.x, dy = py - r0.y, dz = pz - r0.z;
        float e2 = r0.w;                          // log2(opac)
        e2 = fmaf(r1.x, dx * dx, e2);
        e2 = fmaf(r1.y, dy * dy, e2);
        e2 = fmaf(r1.z, dz * dz, e2);
        e2 = fmaf(r1.w, dx * dy, e2);
        e2 = fmaf(r2.x, dy * dz, e2);
        e2 = fmaf(r2.y, dx * dz, e2);
        float w = exp2f(e2);
        w = inbox ? w : 0.0f;
        acc[0]  = fmaf(w, r2.z, acc[0]);
        acc[1]  = fmaf(w, r2.w, acc[1]);
        acc[2]  = fmaf(w, r3.x, acc[2]);
        acc[3]  = fmaf(w, r3.y, acc[3]);
        acc[4]  = fmaf(w, r3.z, acc[4]);
        acc[5]  = fmaf(w, r3.w, acc[5]);
        acc[6]  = fmaf(w, r4.x, acc[6]);
        acc[7]  = fmaf(w, r4.y, acc[7]);
        acc[8]  = fmaf(w, r4.z, acc[8]);
        acc[9]  = fmaf(w, r4.w, acc[9]);
        acc[10] = fmaf(w, r5.x, acc[10]);
        acc[11] = fmaf(w, r5.y, acc[11]);
        acc[12] = fmaf(w, r5.z, acc[12]);
    }

    const long n = (long)gi * (WW * DD) + (long)gj * DD + k;
    float* op = out + n * C_N;
#pragma unroll
    for (int cc = 0; cc < C_N; ++cc) op[cc] = acc[cc];
}

extern "C" void kernel_launch(void* const* d_in, const int* in_sizes, int n_in,
                              void* d_out, int out_size, void* d_ws, size_t ws_size,
                              hipStream_t stream) {
    const float* means  = (const float*)d_in[1];
    const float* opac   = (const float*)d_in[2];
    const float* sem    = (const float*)d_in[3];
    const float* scales = (const float*)d_in[4];
    const float* cov    = (const float*)d_in[5];
    const float* origin = (const float*)d_in[6];
    float* out = (float*)d_out;

    char* ws = (char*)d_ws;
    float* recs   = (float*)ws;                         // 2048*24*4 = 196608 B
    int4*  boxes  = (int4*)(ws + 196608);               // 2048*16   =  32768 B
    int*   counts = (int*)(ws + 196608 + 32768);        // 2025*4, pad to 8192
    int*   lists  = (int*)(ws + 196608 + 32768 + 8192); // 2025*256*4 ~ 2 MiB

    precompute_kernel<<<(P_N + 255) / 256, 256, 0, stream>>>(
        means, opac, sem, scales, cov, origin, recs, boxes);
    build_lists<<<NBRICK, 256, 0, stream>>>(boxes, lists, counts);
    agg_kernel<<<NBRICK, 64, 0, stream>>>(recs, boxes, lists, counts, origin, out);
}

// Round 4
// 110.399 us; speedup vs baseline: 1.0709x; 1.0709x over previous
//
#include <hip/hip_runtime.h>

// LocalAggregator: semantic splatting of P=2048 3D Gaussians onto a 60x60x36
// voxel grid (N=129600 points), C=13 channels.
//
// Round 4 strategy (occupancy fix for the latency-bound agg):
//   K1 precompute: per-Gaussian record (24 floats: mean, log2(opac),
//      -0.5*log2e*icov with 2x folded off-diags, 13 sem, PACKED int box in the
//      pad slot) + int4 box array for the cull kernel.
//   K2 build_lists: survivor list per 4x4x4 brick (2025 bricks x 256 thr).
//   K3 agg: 256 thr/brick = 4 waves. The 4 waves SPLIT THE LIST (entry i goes
//      to wave i%4, ~20 entries each) -> 4x the waves (32/CU, full occupancy)
//      and 4x shorter dependent s_load chains. Partial accumulators reduced
//      4-way through LDS ([4][64][13], lane stride 13 words -> conflict-free).
//      Inner loop reads ONLY the record (box is packed inside) -> a single
//      wave-uniform scalar-load stream per iteration, branch-free body.

constexpr int   HH      = 60;
constexpr int   WW      = 60;
constexpr int   DD      = 36;
constexpr int   P_N     = 2048;
constexpr int   C_N     = 13;
constexpr int   REC     = 24;     // floats per Gaussian record (6 x float4)
constexpr int   BX      = 15;     // bricks in x (60/4)
constexpr int   BY      = 15;     // bricks in y
constexpr int   BZ      = 9;      // bricks in z (36/4)
constexpr int   NBRICK  = BX * BY * BZ;   // 2025
constexpr int   MAXL    = 256;    // list capacity/brick (expected max ~110)
constexpr float GRID_SZ = 0.08f;

__global__ void precompute_kernel(const float* __restrict__ means,
                                  const float* __restrict__ opac,
                                  const float* __restrict__ sem,
                                  const float* __restrict__ scales,
                                  const float* __restrict__ cov,
                                  const float* __restrict__ origin,
                                  float* __restrict__ recs,
                                  int4* __restrict__ boxes) {
    int g = blockIdx.x * blockDim.x + threadIdx.x;
    if (g >= P_N) return;
    float mx = means[g * 3 + 0], my = means[g * 3 + 1], mz = means[g * 3 + 2];
    float sx = scales[g * 3 + 0], sy = scales[g * 3 + 1], sz = scales[g * 3 + 2];
    float smax = fmaxf(sx, fmaxf(sy, sz));
    int rad = (int)ceilf(smax * 3.0f / GRID_SZ);
    float ox = origin[0], oy = origin[1], oz = origin[2];
    // match reference: ((means - origin) / GRID).astype(int32)  (trunc toward 0)
    int mix = (int)((mx - ox) / GRID_SZ);
    int miy = (int)((my - oy) / GRID_SZ);
    int miz = (int)((mz - oz) / GRID_SZ);
    const float* cv = cov + g * 9;
    // packed = (xx, yy, zz, xy, yz, xz) = flat indices [0,4,8,1,5,2]
    float a = cv[0], b = cv[4], c = cv[8], d = cv[1], e = cv[5], f = cv[2];
    float det = a * (b * c - e * e) - d * (d * c - e * f) + f * (d * e - b * f);
    const float kD = -0.5f * 1.44269504088896340736f;  // -0.5 * log2(e)
    const float kO = -1.44269504088896340736f;         // folds the 2x off-diag
    float* r = recs + g * REC;
    r[0] = mx; r[1] = my; r[2] = mz;
    r[3] = __log2f(opac[g]);
    r[4] = kD * (b * c - e * e) / det;   // c_xx
    r[5] = kD * (a * c - f * f) / det;   // c_yy
    r[6] = kD * (a * b - d * d) / det;   // c_zz
    r[7] = kO * (e * f - d * c) / det;   // c_xy
    r[8] = kO * (d * f - a * e) / det;   // c_yz
    r[9] = kO * (d * e - b * f) / det;   // c_xz
#pragma unroll
    for (int cc = 0; cc < C_N; ++cc) r[10 + cc] = sem[g * C_N + cc];
    // pack the int box into the pad slot: coords in [0,60), rad in [2,8]
    unsigned pb = (unsigned)(mix & 0xFF) | ((unsigned)(miy & 0xFF) << 8)
                | ((unsigned)(miz & 0xFF) << 16) | ((unsigned)(rad & 0xFF) << 24);
    r[23] = __int_as_float((int)pb);
    boxes[g] = make_int4(mix, miy, miz, rad);
}

__global__ __launch_bounds__(256) void build_lists(const int4* __restrict__ boxes,
                                                   int* __restrict__ lists,
                                                   int* __restrict__ counts) {
    __shared__ int s_cnt;
    __shared__ int s_idx[MAXL];
    const int b = (int)blockIdx.x;
    const int bk = b % BZ; const int rem = b / BZ;
    const int bj = rem % BY; const int bi = rem / BY;
    const int i0 = bi * 4, j0 = bj * 4, k0 = bk * 4;
    if (threadIdx.x == 0) s_cnt = 0;
    __syncthreads();
    for (int g = (int)threadIdx.x; g < P_N; g += 256) {
        int4 bx = boxes[g];
        bool ov = (bx.x - bx.w <= i0 + 3) && (bx.x + bx.w >= i0)
               && (bx.y - bx.w <= j0 + 3) && (bx.y + bx.w >= j0)
               && (bx.z - bx.w <= k0 + 3) && (bx.z + bx.w >= k0);
        if (ov) {
            int t = atomicAdd(&s_cnt, 1);
            if (t < MAXL) s_idx[t] = g;
        }
    }
    __syncthreads();
    const int c = min(s_cnt, MAXL);
    if (threadIdx.x == 0) counts[b] = c;
    for (int t = (int)threadIdx.x; t < c; t += 256)
        lists[b * MAXL + t] = s_idx[t];
}

__global__ __launch_bounds__(256) void agg_kernel(const float* __restrict__ recs,
                                                  const int* __restrict__ lists,
                                                  const int* __restrict__ counts,
                                                  const float* __restrict__ origin,
                                                  float* __restrict__ out) {
    __shared__ float s_acc[4][64][C_N];   // 13312 B; lane stride 13 words -> no conflicts

    const int b = (int)blockIdx.x;
    const int bk = b % BZ; const int rem = b / BZ;
    const int bj = rem % BY; const int bi = rem / BY;
    const int wave = (int)threadIdx.x >> 6;
    const int lane = (int)threadIdx.x & 63;
    const int kk = lane & 3, lj = (lane >> 2) & 3, li = lane >> 4;
    const int gi = bi * 4 + li, gj = bj * 4 + lj, k = bk * 4 + kk;
    // bit-exact replication of reference pts = (i + 0.5f) * GRID in fp32
    const float px = ((float)gi + 0.5f) * GRID_SZ;
    const float py = ((float)gj + 0.5f) * GRID_SZ;
    const float pz = ((float)k  + 0.5f) * GRID_SZ;
    const float ox = origin[0], oy = origin[1], oz = origin[2];
    const int pix = (int)((px - ox) / GRID_SZ);
    const int piy = (int)((py - oy) / GRID_SZ);
    const int piz = (int)((pz - oz) / GRID_SZ);

    const int cnt = counts[b];
    const int* __restrict__ lst = lists + b * MAXL;

    float acc[C_N];
#pragma unroll
    for (int cc = 0; cc < C_N; ++cc) acc[cc] = 0.0f;

    // each wave handles every 4th list entry; record loads are wave-uniform
    // scalar loads, body is branch-free
#pragma unroll 2
    for (int i = wave; i < cnt; i += 4) {
        const int g = lst[i];
        const float4* rp = (const float4*)(recs + (long)g * REC);
        const float4 r0 = rp[0];   // mean.xyz, log2(opac)
        const float4 r1 = rp[1];   // c_xx c_yy c_zz c_xy
        const float4 r2 = rp[2];   // c_yz c_xz sem0 sem1
        const float4 r3 = rp[3];   // sem2..5
        const float4 r4 = rp[4];   // sem6..9
        const float4 r5 = rp[5];   // sem10..12, packed box
        const unsigned pb = (unsigned)__float_as_int(r5.w);
        const int mx  = (int)(pb & 0xFFu);
        const int my  = (int)((pb >> 8) & 0xFFu);
        const int mzz = (int)((pb >> 16) & 0xFFu);
        const int rad = (int)(pb >> 24);
        const bool inbox = (abs(pix - mx) <= rad)
                        && (abs(piy - my) <= rad)
                        && (abs(piz - mzz) <= rad);
        const float dx = px - r0.x, dy = py - r0.y, dz = pz - r0.z;
        float e2 = r0.w;                          // log2(opac)
        e2 = fmaf(r1.x, dx * dx, e2);
        e2 = fmaf(r1.y, dy * dy, e2);
        e2 = fmaf(r1.z, dz * dz, e2);
        e2 = fmaf(r1.w, dx * dy, e2);
        e2 = fmaf(r2.x, dy * dz, e2);
        e2 = fmaf(r2.y, dx * dz, e2);
        float w = exp2f(e2);
        w = inbox ? w : 0.0f;
        acc[0]  = fmaf(w, r2.z, acc[0]);
        acc[1]  = fmaf(w, r2.w, acc[1]);
        acc[2]  = fmaf(w, r3.x, acc[2]);
        acc[3]  = fmaf(w, r3.y, acc[3]);
        acc[4]  = fmaf(w, r3.z, acc[4]);
        acc[5]  = fmaf(w, r3.w, acc[5]);
        acc[6]  = fmaf(w, r4.x, acc[6]);
        acc[7]  = fmaf(w, r4.y, acc[7]);
        acc[8]  = fmaf(w, r4.z, acc[8]);
        acc[9]  = fmaf(w, r4.w, acc[9]);
        acc[10] = fmaf(w, r5.x, acc[10]);
        acc[11] = fmaf(w, r5.y, acc[11]);
        acc[12] = fmaf(w, r5.z, acc[12]);
    }

    // 4-way cross-wave reduction through LDS, then coalesced-ish output
#pragma unroll
    for (int cc = 0; cc < C_N; ++cc) s_acc[wave][lane][cc] = acc[cc];
    __syncthreads();

    for (int t = (int)threadIdx.x; t < 64 * C_N; t += 256) {
        const int v = t / C_N, c = t % C_N;
        const float s = s_acc[0][v][c] + s_acc[1][v][c]
                      + s_acc[2][v][c] + s_acc[3][v][c];
        const int vk = v & 3, vj = (v >> 2) & 3, vi = v >> 4;
        const long n = (long)(bi * 4 + vi) * (WW * DD)
                     + (long)(bj * 4 + vj) * DD + (bk * 4 + vk);
        out[n * C_N + c] = s;
    }
}

extern "C" void kernel_launch(void* const* d_in, const int* in_sizes, int n_in,
                              void* d_out, int out_size, void* d_ws, size_t ws_size,
                              hipStream_t stream) {
    const float* means  = (const float*)d_in[1];
    const float* opac   = (const float*)d_in[2];
    const float* sem    = (const float*)d_in[3];
    const float* scales = (const float*)d_in[4];
    const float* cov    = (const float*)d_in[5];
    const float* origin = (const float*)d_in[6];
    float* out = (float*)d_out;

    char* ws = (char*)d_ws;
    float* recs   = (float*)ws;                         // 2048*24*4 = 196608 B
    int4*  boxes  = (int4*)(ws + 196608);               // 2048*16   =  32768 B
    int*   counts = (int*)(ws + 196608 + 32768);        // 2025*4, pad to 8192
    int*   lists  = (int*)(ws + 196608 + 32768 + 8192); // 2025*256*4 ~ 2 MiB

    precompute_kernel<<<(P_N + 255) / 256, 256, 0, stream>>>(
        means, opac, sem, scales, cov, origin, recs, boxes);
    build_lists<<<NBRICK, 256, 0, stream>>>(boxes, lists, counts);
    agg_kernel<<<NBRICK, 256, 0, stream>>>(recs, lists, counts, origin, out);
}

// Round 5
// 93.251 us; speedup vs baseline: 1.2678x; 1.1839x over previous
//
#include <hip/hip_runtime.h>

// LocalAggregator: semantic splatting of P=2048 3D Gaussians onto a 60x60x36
// voxel grid (N=129600 points), C=13 channels.
//
// Round 5 strategy (serialized-load fix + kernel fusion):
//   K1 precompute: per-Gaussian record (24 floats: mean, log2(opac),
//      -0.5*log2e*icov with 2x folded off-diags, 13 sem, packed int box) +
//      int4 box array for culling.
//   K2 agg (fused cull + eval), 2025 blocks x 256 thr (4x4x4 brick):
//      a) cull: 8 coalesced int4 box tests/thread, LDS-atomic compaction.
//      b) stage: survivors' 96B records copied to LDS by parallel coalesced
//         float4 loads (ONE latency event, not ~78 serial uniform loads —
//         this was R4's bottleneck: the dependent lst[i]->recs[g] global
//         chain didn't overlap even at 32 waves/CU).
//      c) eval: 4 waves split the list; broadcast ds_read_b128 from LDS,
//         branch-free body, per-thread fp32 accumulators.
//      d) 4-way cross-wave LDS reduce (buffer overlaid on s_rec) + store.
//      LDS ~14.6KB/block -> 8 blocks/CU -> 32 waves/CU.

constexpr int   HH      = 60;
constexpr int   WW      = 60;
constexpr int   DD      = 36;
constexpr int   P_N     = 2048;
constexpr int   C_N     = 13;
constexpr int   REC     = 24;     // floats per record (6 x float4)
constexpr int   BXD     = 15;     // bricks in x (60/4)
constexpr int   BYD     = 15;     // bricks in y
constexpr int   BZD     = 9;      // bricks in z (36/4)
constexpr int   NBRICK  = BXD * BYD * BZD;   // 2025
constexpr int   MAXL    = 256;    // list capacity (observed max ~110, passes)
constexpr int   CAP     = 128;    // records staged in LDS per batch
constexpr float GRID_SZ = 0.08f;

__global__ void precompute_kernel(const float* __restrict__ means,
                                  const float* __restrict__ opac,
                                  const float* __restrict__ sem,
                                  const float* __restrict__ scales,
                                  const float* __restrict__ cov,
                                  const float* __restrict__ origin,
                                  float* __restrict__ recs,
                                  int4* __restrict__ boxes) {
    int g = blockIdx.x * blockDim.x + threadIdx.x;
    if (g >= P_N) return;
    float mx = means[g * 3 + 0], my = means[g * 3 + 1], mz = means[g * 3 + 2];
    float sx = scales[g * 3 + 0], sy = scales[g * 3 + 1], sz = scales[g * 3 + 2];
    float smax = fmaxf(sx, fmaxf(sy, sz));
    int rad = (int)ceilf(smax * 3.0f / GRID_SZ);
    float ox = origin[0], oy = origin[1], oz = origin[2];
    // match reference: ((means - origin) / GRID).astype(int32)  (trunc toward 0)
    int mix = (int)((mx - ox) / GRID_SZ);
    int miy = (int)((my - oy) / GRID_SZ);
    int miz = (int)((mz - oz) / GRID_SZ);
    const float* cv = cov + g * 9;
    // packed = (xx, yy, zz, xy, yz, xz) = flat indices [0,4,8,1,5,2]
    float a = cv[0], b = cv[4], c = cv[8], d = cv[1], e = cv[5], f = cv[2];
    float det = a * (b * c - e * e) - d * (d * c - e * f) + f * (d * e - b * f);
    const float kD = -0.5f * 1.44269504088896340736f;  // -0.5 * log2(e)
    const float kO = -1.44269504088896340736f;         // folds the 2x off-diag
    float* r = recs + g * REC;
    r[0] = mx; r[1] = my; r[2] = mz;
    r[3] = __log2f(opac[g]);
    r[4] = kD * (b * c - e * e) / det;   // c_xx
    r[5] = kD * (a * c - f * f) / det;   // c_yy
    r[6] = kD * (a * b - d * d) / det;   // c_zz
    r[7] = kO * (e * f - d * c) / det;   // c_xy
    r[8] = kO * (d * f - a * e) / det;   // c_yz
    r[9] = kO * (d * e - b * f) / det;   // c_xz
#pragma unroll
    for (int cc = 0; cc < C_N; ++cc) r[10 + cc] = sem[g * C_N + cc];
    // pack the int box into the pad slot: coords in [0,60), rad in [2,8]
    unsigned pb = (unsigned)(mix & 0xFF) | ((unsigned)(miy & 0xFF) << 8)
                | ((unsigned)(miz & 0xFF) << 16) | ((unsigned)(rad & 0xFF) << 24);
    r[23] = __int_as_float((int)pb);
    boxes[g] = make_int4(mix, miy, miz, rad);
}

__global__ __launch_bounds__(256) void agg_kernel(const float* __restrict__ recs,
                                                  const int4* __restrict__ boxes,
                                                  const float* __restrict__ origin,
                                                  float* __restrict__ out) {
    __shared__ int s_idx[MAXL];
    __shared__ int s_cnt;
    // overlay: staged records (CAP*6 float4 = 12.3KB) / reduce buf (13.3KB)
    __shared__ float4 s_mem[4 * 64 * C_N / 4 + 4];   // 13.4KB, 16B aligned
    float4* s_rec4 = s_mem;                           // [CAP][6]
    float (*s_acc)[64][C_N] = (float (*)[64][C_N])s_mem;

    const int b = (int)blockIdx.x;
    const int bk = b % BZD; const int rem = b / BZD;
    const int bj = rem % BYD; const int bi = rem / BYD;
    const int i0 = bi * 4, j0 = bj * 4, k0 = bk * 4;

    if (threadIdx.x == 0) s_cnt = 0;
    __syncthreads();

    // --- cull: coalesced box tests, LDS compaction ---
    for (int g = (int)threadIdx.x; g < P_N; g += 256) {
        int4 bx = boxes[g];
        bool ov = (bx.x - bx.w <= i0 + 3) && (bx.x + bx.w >= i0)
               && (bx.y - bx.w <= j0 + 3) && (bx.y + bx.w >= j0)
               && (bx.z - bx.w <= k0 + 3) && (bx.z + bx.w >= k0);
        if (ov) {
            int t = atomicAdd(&s_cnt, 1);
            if (t < MAXL) s_idx[t] = g;
        }
    }
    __syncthreads();
    const int cnt = min(s_cnt, MAXL);

    // --- this thread's voxel ---
    const int wave = (int)threadIdx.x >> 6;
    const int lane = (int)threadIdx.x & 63;
    const int kk = lane & 3, lj = (lane >> 2) & 3, li = lane >> 4;
    const int gi = i0 + li, gj = j0 + lj, k = k0 + kk;
    // bit-exact replication of reference pts = (i + 0.5f) * GRID in fp32
    const float px = ((float)gi + 0.5f) * GRID_SZ;
    const float py = ((float)gj + 0.5f) * GRID_SZ;
    const float pz = ((float)k  + 0.5f) * GRID_SZ;
    const float ox = origin[0], oy = origin[1], oz = origin[2];
    const int pix = (int)((px - ox) / GRID_SZ);
    const int piy = (int)((py - oy) / GRID_SZ);
    const int piz = (int)((pz - oz) / GRID_SZ);

    float acc[C_N];
#pragma unroll
    for (int cc = 0; cc < C_N; ++cc) acc[cc] = 0.0f;

    // --- batched: stage records to LDS (coalesced), eval from LDS ---
    for (int base = 0; base < cnt; base += CAP) {
        const int nb = min(CAP, cnt - base);
        __syncthreads();   // protect s_mem reuse (prev eval / reduce overlay)
        for (int t = (int)threadIdx.x; t < nb * 6; t += 256) {
            const int e = t / 6, part = t % 6;
            const int g = s_idx[base + e];
            s_rec4[e * 6 + part] =
                ((const float4*)(recs + (long)g * REC))[part];
        }
        __syncthreads();
        // 4 waves split the staged batch; broadcast ds_reads, branch-free
#pragma unroll 2
        for (int i = wave; i < nb; i += 4) {
            const float4 r0 = s_rec4[i * 6 + 0];   // mean.xyz, log2(opac)
            const float4 r1 = s_rec4[i * 6 + 1];   // c_xx c_yy c_zz c_xy
            const float4 r2 = s_rec4[i * 6 + 2];   // c_yz c_xz sem0 sem1
            const float4 r3 = s_rec4[i * 6 + 3];   // sem2..5
            const float4 r4 = s_rec4[i * 6 + 4];   // sem6..9
            const float4 r5 = s_rec4[i * 6 + 5];   // sem10..12, packed box
            const unsigned pb = (unsigned)__float_as_int(r5.w);
            const int mx  = (int)(pb & 0xFFu);
            const int my  = (int)((pb >> 8) & 0xFFu);
            const int mzz = (int)((pb >> 16) & 0xFFu);
            const int rad = (int)(pb >> 24);
            const bool inbox = (abs(pix - mx) <= rad)
                            && (abs(piy - my) <= rad)
                            && (abs(piz - mzz) <= rad);
            const float dx = px - r0.x, dy = py - r0.y, dz = pz - r0.z;
            float e2 = r0.w;                       // log2(opac)
            e2 = fmaf(r1.x, dx * dx, e2);
            e2 = fmaf(r1.y, dy * dy, e2);
            e2 = fmaf(r1.z, dz * dz, e2);
            e2 = fmaf(r1.w, dx * dy, e2);
            e2 = fmaf(r2.x, dy * dz, e2);
            e2 = fmaf(r2.y, dx * dz, e2);
            float w = exp2f(e2);
            w = inbox ? w : 0.0f;
            acc[0]  = fmaf(w, r2.z, acc[0]);
            acc[1]  = fmaf(w, r2.w, acc[1]);
            acc[2]  = fmaf(w, r3.x, acc[2]);
            acc[3]  = fmaf(w, r3.y, acc[3]);
            acc[4]  = fmaf(w, r3.z, acc[4]);
            acc[5]  = fmaf(w, r3.w, acc[5]);
            acc[6]  = fmaf(w, r4.x, acc[6]);
            acc[7]  = fmaf(w, r4.y, acc[7]);
            acc[8]  = fmaf(w, r4.z, acc[8]);
            acc[9]  = fmaf(w, r4.w, acc[9]);
            acc[10] = fmaf(w, r5.x, acc[10]);
            acc[11] = fmaf(w, r5.y, acc[11]);
            acc[12] = fmaf(w, r5.z, acc[12]);
        }
    }

    // --- 4-way cross-wave reduction (s_acc overlays s_rec4) + store ---
    __syncthreads();
#pragma unroll
    for (int cc = 0; cc < C_N; ++cc) s_acc[wave][lane][cc] = acc[cc];
    __syncthreads();

    for (int t = (int)threadIdx.x; t < 64 * C_N; t += 256) {
        const int v = t / C_N, c = t % C_N;
        const float s = s_acc[0][v][c] + s_acc[1][v][c]
                      + s_acc[2][v][c] + s_acc[3][v][c];
        const int vk = v & 3, vj = (v >> 2) & 3, vi = v >> 4;
        const long n = (long)(i0 + vi) * (WW * DD)
                     + (long)(j0 + vj) * DD + (k0 + vk);
        out[n * C_N + c] = s;
    }
}

extern "C" void kernel_launch(void* const* d_in, const int* in_sizes, int n_in,
                              void* d_out, int out_size, void* d_ws, size_t ws_size,
                              hipStream_t stream) {
    const float* means  = (const float*)d_in[1];
    const float* opac   = (const float*)d_in[2];
    const float* sem    = (const float*)d_in[3];
    const float* scales = (const float*)d_in[4];
    const float* cov    = (const float*)d_in[5];
    const float* origin = (const float*)d_in[6];
    float* out = (float*)d_out;

    char* ws = (char*)d_ws;
    float* recs  = (float*)ws;             // 2048*24*4 = 196608 B
    int4*  boxes = (int4*)(ws + 196608);   // 2048*16   =  32768 B

    precompute_kernel<<<(P_N + 255) / 256, 256, 0, stream>>>(
        means, opac, sem, scales, cov, origin, recs, boxes);
    agg_kernel<<<NBRICK, 256, 0, stream>>>(recs, boxes, origin, out);
}

// Round 6
// 86.227 us; speedup vs baseline: 1.3711x; 1.0815x over previous
//
#include <hip/hip_runtime.h>

// LocalAggregator: semantic splatting of P=2048 3D Gaussians onto a 60x60x36
// voxel grid (N=129600 points), C=13 channels.
//
// Round 6 strategy (scalar-pipe eval):
//   K1 precompute: per-Gaussian record (24 floats: mean, log2(opac),
//      -0.5*log2e*icov with 2x folded off-diags, 13 sem) + int4 box array.
//   K2 agg, 2025 blocks x 256 thr (4x4x4 brick, 4 waves split the list):
//      a) cull: coalesced box tests; survivors stored in LDS as
//         g | xmask<<12 | ymask<<16 | zmask<<20 (per-axis 4-bit in-brick
//         masks) -> the per-voxel inbox test in eval collapses to
//         (ent & sel) == sel with a lane-constant sel (2 VALU ops).
//      b) eval: record read via wave-uniform SGPR loads (readfirstlane ->
//         s_load_dwordx8/16). NO LDS staging, NO LDS data-return pressure
//         (R5's 6x broadcast ds_read_b128/iter = ~24 clk/iter/CU shared by
//         all 32 waves was the structural floor), no staging barriers.
//         ~31 VALU/iter, unroll 2, 8 waves/SIMD hide the ~200cy SMEM latency.
//      c) 4-way cross-wave LDS reduce + store.

constexpr int   HH      = 60;
constexpr int   WW      = 60;
constexpr int   DD      = 36;
constexpr int   P_N     = 2048;
constexpr int   C_N     = 13;
constexpr int   REC     = 24;     // floats per record (6 x float4)
constexpr int   BXD     = 15;     // bricks in x (60/4)
constexpr int   BYD     = 15;     // bricks in y
constexpr int   BZD     = 9;      // bricks in z (36/4)
constexpr int   NBRICK  = BXD * BYD * BZD;   // 2025
constexpr int   MAXL    = 256;    // list capacity (observed max ~110)
constexpr float GRID_SZ = 0.08f;

__global__ void precompute_kernel(const float* __restrict__ means,
                                  const float* __restrict__ opac,
                                  const float* __restrict__ sem,
                                  const float* __restrict__ scales,
                                  const float* __restrict__ cov,
                                  const float* __restrict__ origin,
                                  float* __restrict__ recs,
                                  int4* __restrict__ boxes) {
    int g = blockIdx.x * blockDim.x + threadIdx.x;
    if (g >= P_N) return;
    float mx = means[g * 3 + 0], my = means[g * 3 + 1], mz = means[g * 3 + 2];
    float sx = scales[g * 3 + 0], sy = scales[g * 3 + 1], sz = scales[g * 3 + 2];
    float smax = fmaxf(sx, fmaxf(sy, sz));
    int rad = (int)ceilf(smax * 3.0f / GRID_SZ);
    float ox = origin[0], oy = origin[1], oz = origin[2];
    // match reference: ((means - origin) / GRID).astype(int32)  (trunc toward 0)
    int mix = (int)((mx - ox) / GRID_SZ);
    int miy = (int)((my - oy) / GRID_SZ);
    int miz = (int)((mz - oz) / GRID_SZ);
    const float* cv = cov + g * 9;
    // packed = (xx, yy, zz, xy, yz, xz) = flat indices [0,4,8,1,5,2]
    float a = cv[0], b = cv[4], c = cv[8], d = cv[1], e = cv[5], f = cv[2];
    float det = a * (b * c - e * e) - d * (d * c - e * f) + f * (d * e - b * f);
    const float kD = -0.5f * 1.44269504088896340736f;  // -0.5 * log2(e)
    const float kO = -1.44269504088896340736f;         // folds the 2x off-diag
    float* r = recs + g * REC;
    r[0] = mx; r[1] = my; r[2] = mz;
    r[3] = __log2f(opac[g]);
    r[4] = kD * (b * c - e * e) / det;   // c_xx
    r[5] = kD * (a * c - f * f) / det;   // c_yy
    r[6] = kD * (a * b - d * d) / det;   // c_zz
    r[7] = kO * (e * f - d * c) / det;   // c_xy
    r[8] = kO * (d * f - a * e) / det;   // c_yz
    r[9] = kO * (d * e - b * f) / det;   // c_xz
#pragma unroll
    for (int cc = 0; cc < C_N; ++cc) r[10 + cc] = sem[g * C_N + cc];
    r[23] = 0.0f;
    boxes[g] = make_int4(mix, miy, miz, rad);
}

__global__ __launch_bounds__(256) void agg_kernel(const float* __restrict__ recs,
                                                  const int4* __restrict__ boxes,
                                                  float* __restrict__ out) {
    __shared__ int   s_idx[MAXL];
    __shared__ int   s_cnt;
    __shared__ float s_acc[4][64][C_N];   // 13312 B; stride 13 words -> no conflicts

    const int b = (int)blockIdx.x;
    const int bk = b % BZD; const int rem = b / BZD;
    const int bj = rem % BYD; const int bi = rem / BYD;
    const int i0 = bi * 4, j0 = bj * 4, k0 = bk * 4;

    if (threadIdx.x == 0) s_cnt = 0;
    __syncthreads();

    // --- cull: coalesced box tests; pack per-axis in-brick masks ---
    for (int g = (int)threadIdx.x; g < P_N; g += 256) {
        int4 bx = boxes[g];
        bool ov = (bx.x - bx.w <= i0 + 3) && (bx.x + bx.w >= i0)
               && (bx.y - bx.w <= j0 + 3) && (bx.y + bx.w >= j0)
               && (bx.z - bx.w <= k0 + 3) && (bx.z + bx.w >= k0);
        if (ov) {
            // per-axis masks: bit o set iff |i0+o - center| <= rad  (o in 0..3)
            int xlo = max(bx.x - bx.w - i0, 0), xhi = min(bx.x + bx.w - i0, 3);
            int ylo = max(bx.y - bx.w - j0, 0), yhi = min(bx.y + bx.w - j0, 3);
            int zlo = max(bx.z - bx.w - k0, 0), zhi = min(bx.z + bx.w - k0, 3);
            unsigned mx4 = (0xFu >> (3 - xhi)) & (0xFu << xlo);
            unsigned my4 = (0xFu >> (3 - yhi)) & (0xFu << ylo);
            unsigned mz4 = (0xFu >> (3 - zhi)) & (0xFu << zlo);
            unsigned ent = (unsigned)g | (mx4 << 12) | (my4 << 16) | (mz4 << 20);
            int t = atomicAdd(&s_cnt, 1);
            if (t < MAXL) s_idx[t] = (int)ent;
        }
    }
    __syncthreads();
    const int cnt = min(s_cnt, MAXL);

    // --- this thread's voxel ---
    const int wave = (int)threadIdx.x >> 6;
    const int lane = (int)threadIdx.x & 63;
    const int kk = lane & 3, lj = (lane >> 2) & 3, li = lane >> 4;
    const int gi = i0 + li, gj = j0 + lj, k = k0 + kk;
    // bit-exact replication of reference pts = (i + 0.5f) * GRID in fp32
    const float px = ((float)gi + 0.5f) * GRID_SZ;
    const float py = ((float)gj + 0.5f) * GRID_SZ;
    const float pz = ((float)k  + 0.5f) * GRID_SZ;
    // lane-constant selector: inbox <=> (ent & sel) == sel
    const unsigned sel = (1u << (12 + li)) | (1u << (16 + lj)) | (1u << (20 + kk));

    float acc[C_N];
#pragma unroll
    for (int cc = 0; cc < C_N; ++cc) acc[cc] = 0.0f;

    // --- eval: 4 waves split the list; records via wave-uniform SGPR loads ---
#pragma unroll 2
    for (int i = wave; i < cnt; i += 4) {
        const unsigned ent = (unsigned)__builtin_amdgcn_readfirstlane(s_idx[i]);
        const int g = (int)(ent & 0xFFFu);
        const float* __restrict__ r = recs + (long)g * REC;  // uniform -> s_load
        const bool inbox = (ent & sel) == sel;
        const float dx = px - r[0], dy = py - r[1], dz = pz - r[2];
        float e2 = r[3];                       // log2(opac)
        e2 = fmaf(r[4], dx * dx, e2);
        e2 = fmaf(r[5], dy * dy, e2);
        e2 = fmaf(r[6], dz * dz, e2);
        e2 = fmaf(r[7], dx * dy, e2);
        e2 = fmaf(r[8], dy * dz, e2);
        e2 = fmaf(r[9], dx * dz, e2);
        float w = exp2f(e2);
        w = inbox ? w : 0.0f;
#pragma unroll
        for (int cc = 0; cc < C_N; ++cc)
            acc[cc] = fmaf(w, r[10 + cc], acc[cc]);
    }

    // --- 4-way cross-wave reduction + store ---
#pragma unroll
    for (int cc = 0; cc < C_N; ++cc) s_acc[wave][lane][cc] = acc[cc];
    __syncthreads();

    for (int t = (int)threadIdx.x; t < 64 * C_N; t += 256) {
        const int v = t / C_N, c = t % C_N;
        const float s = s_acc[0][v][c] + s_acc[1][v][c]
                      + s_acc[2][v][c] + s_acc[3][v][c];
        const int vk = v & 3, vj = (v >> 2) & 3, vi = v >> 4;
        const long n = (long)(i0 + vi) * (WW * DD)
                     + (long)(j0 + vj) * DD + (k0 + vk);
        out[n * C_N + c] = s;
    }
}

extern "C" void kernel_launch(void* const* d_in, const int* in_sizes, int n_in,
                              void* d_out, int out_size, void* d_ws, size_t ws_size,
                              hipStream_t stream) {
    const float* means  = (const float*)d_in[1];
    const float* opac   = (const float*)d_in[2];
    const float* sem    = (const float*)d_in[3];
    const float* scales = (const float*)d_in[4];
    const float* cov    = (const float*)d_in[5];
    const float* origin = (const float*)d_in[6];
    float* out = (float*)d_out;

    char* ws = (char*)d_ws;
    float* recs  = (float*)ws;             // 2048*24*4 = 196608 B
    int4*  boxes = (int4*)(ws + 196608);   // 2048*16   =  32768 B

    precompute_kernel<<<(P_N + 255) / 256, 256, 0, stream>>>(
        means, opac, sem, scales, cov, origin, recs, boxes);
    agg_kernel<<<NBRICK, 256, 0, stream>>>(recs, boxes, out);
}